// Round 8
// baseline (1663.100 us; speedup 1.0000x reference)
//
#include <hip/hip_runtime.h>
#include <stdint.h>

#define NPTS 4096
#define BATCH 8
#define KNN 16

typedef __attribute__((ext_vector_type(8))) short short8;
typedef __attribute__((ext_vector_type(4))) float f32x4;
typedef unsigned long long u64;

// ---------------- 1x1 conv: Y[b,co,n] = bias[co] + sum_ci W[co,ci]*X[b,ci,n]
template<int CIN, int COTILE>
__global__ __launch_bounds__(256) void conv_kernel(
    const float* __restrict__ X, const float* __restrict__ W,
    const float* __restrict__ bias, float* __restrict__ Y, int cout) {
    int n = blockIdx.x * 256 + threadIdx.x;
    int co0 = blockIdx.y * COTILE;
    int b = blockIdx.z;
    const float* xb = X + (size_t)b * CIN * NPTS + n;
    float acc[COTILE];
#pragma unroll
    for (int j = 0; j < COTILE; ++j) acc[j] = bias[co0 + j];
    for (int ci = 0; ci < CIN; ++ci) {
        float xv = xb[(size_t)ci * NPTS];
#pragma unroll
        for (int j = 0; j < COTILE; ++j)
            acc[j] = fmaf(W[(co0 + j) * CIN + ci], xv, acc[j]);
    }
#pragma unroll
    for (int j = 0; j < COTILE; ++j)
        Y[((size_t)b * cout + co0 + j) * NPTS + n] = acc[j];
}

// ---------------- LayerNorm over point axis + affine + ReLU, in place -------
__global__ __launch_bounds__(256) void ln_relu_kernel(
    float* __restrict__ X, const float* __restrict__ g,
    const float* __restrict__ be, int C) {
    __shared__ float row_s[NPTS];
    __shared__ double sh[256], sh2[256];
    int c = blockIdx.x, b = blockIdx.y, t = threadIdx.x;
    float* row = X + ((size_t)b * C + c) * NPTS;
    double s = 0.0, s2 = 0.0;
    for (int i = t * 4; i < NPTS; i += 1024) {
        f32x4 v = *(const f32x4*)(row + i);
        *(f32x4*)(row_s + i) = v;
        s += (double)v.x + (double)v.y + (double)v.z + (double)v.w;
        s2 += (double)v.x * v.x + (double)v.y * v.y
            + (double)v.z * v.z + (double)v.w * v.w;
    }
    sh[t] = s; sh2[t] = s2;
    __syncthreads();
    for (int off = 128; off > 0; off >>= 1) {
        if (t < off) { sh[t] += sh[t + off]; sh2[t] += sh2[t + off]; }
        __syncthreads();
    }
    double mu = sh[0] / (double)NPTS;
    double var = sh2[0] / (double)NPTS - mu * mu;
    float rstd = (float)(1.0 / sqrt(var + 1e-5));
    float muf = (float)mu;
    for (int i = t * 4; i < NPTS; i += 1024) {
        f32x4 v = *(const f32x4*)(row_s + i);
        f32x4 gg = *(const f32x4*)(g + i);
        f32x4 bb = *(const f32x4*)(be + i);
        f32x4 o;
        o.x = fmaxf((v.x - muf) * rstd * gg.x + bb.x, 0.f);
        o.y = fmaxf((v.y - muf) * rstd * gg.y + bb.y, 0.f);
        o.z = fmaxf((v.z - muf) * rstd * gg.z + bb.z, 0.f);
        o.w = fmaxf((v.w - muf) * rstd * gg.w + bb.w, 0.f);
        *(f32x4*)(row + i) = o;
    }
}

// ---------------- bf16 hi/lo split conversion + fused squared norms ----------
// Fragment-major layout: k in [0,512) (hi: k=c, lo: k=256+c), per (ks32=k>>5,
// R=n>>4): 4 quads x 16 rows x 8 bf16 = 1 KB contiguous block; lane addr in the
// knn kernel = block_base + lane*16 -> perfectly coalesced 1 KB fragment loads.
__device__ inline unsigned short f2bf_rne(float x) {
    union { float f; unsigned u; } v; v.f = x;
    unsigned u = v.u;
    return (unsigned short)((u + 0x7FFFu + ((u >> 16) & 1u)) >> 16);
}
__device__ inline float bf2f(unsigned short h) {
    union { float f; unsigned u; } v; v.u = ((unsigned)h) << 16;
    return v.f;
}
__device__ inline size_t frag_off16(int k, int R, int l15) {
    return ((size_t)(((k >> 5) * 256 + R) * 4 + ((k >> 3) & 3))) * 128 + l15 * 8;
}

__global__ __launch_bounds__(256) void convert_kernel(
    const float* __restrict__ X2, unsigned short* __restrict__ Fc2,
    float* __restrict__ SQ) {
    __shared__ float T[64][65];
    __shared__ float Q[64][4];
    int b = blockIdx.y;
    int n0 = blockIdx.x * 64;
    int t = threadIdx.x;
    int n_loc = t >> 2, cq = t & 3;
    int n = n0 + n_loc;
    int R = n >> 4, l15 = n & 15;
    unsigned short* Fb = Fc2 + (size_t)b * 2097152;
    float sacc = 0.f;
    for (int cc = 0; cc < 4; ++cc) {
        for (int r = 0; r < 16; ++r) {
            int cl = r * 4 + (t >> 6);
            T[cl][t & 63] = X2[((size_t)b * 256 + cc * 64 + cl) * NPTS + n0 + (t & 63)];
        }
        __syncthreads();
#pragma unroll
        for (int oo = 0; oo < 2; ++oo) {
            int o = cq * 2 + oo;            // octet within this 64-ch chunk
            short8 hv, lv;
#pragma unroll
            for (int j = 0; j < 8; ++j) {
                float x = T[o * 8 + j][n_loc];
                sacc = fmaf(x, x, sacc);
                unsigned short h = f2bf_rne(x);
                float lo = x - bf2f(h);
                hv[j] = (short)h;
                lv[j] = (short)f2bf_rne(lo);
            }
            int k1 = cc * 64 + o * 8;
            *(short8*)(Fb + frag_off16(k1, R, l15)) = hv;
            *(short8*)(Fb + frag_off16(256 + k1, R, l15)) = lv;
        }
        __syncthreads();
    }
    Q[n_loc][cq] = sacc;
    __syncthreads();
    if (t < 64)
        SQ[(size_t)b * NPTS + n0 + t] = Q[t][0] + Q[t][1] + Q[t][2] + Q[t][3];
}

// ---------------- fused MFMA kNN: barrier-free K-loop, LDS top-k lists -------
// grid (8 batch, 32 q-tiles, 4 key-splits). 4 waves in 2x2 (64q x 64k each).
// Fragments global->VGPR (coalesced 1 KB), dbuf over 16 K=32 steps.
// Per-thread top-16 list lives in LDS (mls[256][17] u64, stride-17 = 2-way free)
// -> 32 fewer VGPRs -> 3 waves/SIMD. Gbuf is a 32-key quarter (16.9 KB) so
// total LDS 51712 B also allows 3 WGs/CU.
#define SENT 0x7F800000FFFFFFFFull   // d=+inf sentinel
#define GBUF_B 16896                 // 32 * 132 * 4
#define MLS_OFF GBUF_B
#define SMEM_B (GBUF_B + 34816)      // + 256*17*8

__global__ __launch_bounds__(256) void knn_mfma_kernel(
    const unsigned short* __restrict__ Fc2, const float* __restrict__ SQ,
    u64* __restrict__ DpA, u64* __restrict__ DpB) {
    __shared__ __align__(16) char smem[SMEM_B];
    int b = blockIdx.x;
    int q0 = blockIdx.y * 128;
    int ks = blockIdx.z;
    int t = threadIdx.x;
    int lane = t & 63;
    int wv = t >> 6;
    int wq = wv & 1, wk = wv >> 1;
    int quad = lane >> 4;
    int l15 = lane & 15;
    const float* sqb = SQ + (size_t)b * NPTS;
    const char* FcB = (const char*)Fc2 + (size_t)b * 4194304;
    float sqn = sqb[q0 + (t & 127)];
    int RA = (q0 >> 4) + wq * 4;          // A row-block base (16-row units)
    int voff = lane * 16;

    u64* myl = (u64*)(smem + MLS_OFF) + t * 17;
#pragma unroll
    for (int j = 0; j < KNN; ++j) myl[j] = SENT;

    for (int kt = 0; kt < 8; ++kt) {
        int kbase = ks * 1024 + kt * 128;
        int RB = (kbase >> 4) + wk * 4;
        f32x4 acc[4][4];
#pragma unroll
        for (int i = 0; i < 4; ++i)
#pragma unroll
            for (int j = 0; j < 4; ++j) acc[i][j] = (f32x4){0.f, 0.f, 0.f, 0.f};

        short8 abuf[2][4], bbuf[2][4];
#pragma unroll
        for (int x = 0; x < 4; ++x) {
            abuf[0][x] = *(const short8*)(FcB + (size_t)((RA + x) * 1024) + voff);
            bbuf[0][x] = *(const short8*)(FcB + (size_t)((RB + x) * 1024) + voff);
        }
#pragma unroll
        for (int s = 0; s < 16; ++s) {
            int cur = s & 1, nxt = cur ^ 1;
            if (s < 15) {
#pragma unroll
                for (int x = 0; x < 4; ++x) {
                    abuf[nxt][x] = *(const short8*)(FcB + (size_t)(((s + 1) * 256 + RA + x) * 1024) + voff);
                    bbuf[nxt][x] = *(const short8*)(FcB + (size_t)(((s + 1) * 256 + RB + x) * 1024) + voff);
                }
            }
#pragma unroll
            for (int tq = 0; tq < 4; ++tq)
#pragma unroll
                for (int tk = 0; tk < 4; ++tk)
                    acc[tq][tk] = __builtin_amdgcn_mfma_f32_16x16x32_bf16(
                        abuf[cur][tq], bbuf[cur][tk], acc[tq][tk], 0, 0, 0);
        }

        // selection: four 32-key quarters through Gbuf [key][query+pad] stride 132
        float* Gbuf = (float*)smem;
        int q = t & 127, sub = t >> 7;
#pragma unroll 1
        for (int hh = 0; hh < 4; ++hh) {
            __syncthreads();   // previous Gbuf consumers done
            if (wk == (hh >> 1)) {
#pragma unroll
                for (int tp = 0; tp < 2; ++tp) {
                    int tk = (hh & 1) * 2 + tp;
                    int klocal = tp * 16 + l15;
#pragma unroll
                    for (int tq = 0; tq < 4; ++tq)
                        *(f32x4*)(Gbuf + klocal * 132 + wq * 64 + tq * 16 + quad * 4) = acc[tq][tk];
                }
            }
            __syncthreads();
            // phase 1: uniform-cost filter, store true distance back in place
            float* gq = Gbuf + sub * 16 * 132 + q;
            float thrf = __uint_as_float((unsigned)(myl[KNN - 1] >> 32));
            unsigned mask = 0;
#pragma unroll
            for (int j = 0; j < 16; ++j) {
                float gv = gq[j * 132];
                float d = fmaxf(fmaf(-2.f, gv, sqn + sqb[kbase + hh * 32 + sub * 16 + j]), 0.f);
                gq[j * 132] = d;
                mask |= (d <= thrf) ? (1u << j) : 0u;
            }
            // phase 2: process only candidates (wave cost = max popcount over lanes)
            while (__any((int)(mask != 0u))) {
                if (mask) {
                    int j = __ffs(mask) - 1;
                    mask &= mask - 1u;
                    float d = gq[j * 132];
                    u64 pk = ((u64)__float_as_uint(d) << 32)
                           | (unsigned)(kbase + hh * 32 + sub * 16 + j);
                    if (pk < myl[KNN - 1]) {
                        int s2 = KNN - 1;
                        for (; s2 > 0; --s2) {
                            u64 pv = myl[s2 - 1];
                            if (pv > pk) myl[s2] = pv; else break;
                        }
                        myl[s2] = pk;
                    }
                }
            }
        }
    }

    // merge the two per-query sublists (threads t and t+128) - already in LDS
    __syncthreads();
    u64* mls = (u64*)(smem + MLS_OFF);
    if (t < 128) {
        const u64* da = mls + t * 17;
        const u64* db = mls + (t + 128) * 17;
        u64* outp = ((ks < 2) ? DpA : DpB)
                  + ((size_t)((b * NPTS + q0 + t) * 2 + (ks & 1))) * KNN;
        int ia = 0, ib2 = 0;
        for (int k = 0; k < KNN; ++k) {
            bool ta = (ib2 >= KNN) || (ia < KNN && da[ia] < db[ib2]);
            outp[k] = ta ? da[ia++] : db[ib2++];
        }
    }
}

// ---------------- merge 4 key-split partial lists per query ------------------
__global__ __launch_bounds__(256) void knn_merge4_kernel(
    const u64* __restrict__ DpA, const u64* __restrict__ DpB,
    int* __restrict__ IDX) {
    int qg = blockIdx.x * 256 + threadIdx.x;          // [0, B*NPTS)
    const u64* L0 = DpA + (size_t)qg * 2 * KNN;
    const u64* L1 = L0 + KNN;
    const u64* L2 = DpB + (size_t)qg * 2 * KNN;
    const u64* L3 = L2 + KNN;
    int p0 = 0, p1 = 0, p2 = 0, p3 = 0;
    int* outp = IDX + (size_t)qg * KNN;
#pragma unroll 1
    for (int k = 0; k < KNN; ++k) {
        u64 v0 = (p0 < KNN) ? L0[p0] : ~0ull;
        u64 v1 = (p1 < KNN) ? L1[p1] : ~0ull;
        u64 v2 = (p2 < KNN) ? L2[p2] : ~0ull;
        u64 v3 = (p3 < KNN) ? L3[p3] : ~0ull;
        u64 best = v0; int bl = 0;
        if (v1 < best) { best = v1; bl = 1; }
        if (v2 < best) { best = v2; bl = 2; }
        if (v3 < best) { best = v3; bl = 3; }
        outp[k] = (int)(best & 0xffffffffull);
        if (bl == 0) ++p0; else if (bl == 1) ++p1; else if (bl == 2) ++p2; else ++p3;
    }
}

// ---------------- transpose: X2 [b][c][n] -> Xt [b][n][256] ------------------
__global__ __launch_bounds__(256) void transpose_kernel(
    const float* __restrict__ X2, float* __restrict__ Xt) {
    __shared__ float T[64][65];
    int b = blockIdx.x;
    int n0 = blockIdx.y * 64;
    int t = threadIdx.x;
    int wave = t >> 6, lane = t & 63;
    for (int cc = 0; cc < 4; ++cc) {
        for (int r = 0; r < 16; ++r) {
            int cl = r * 4 + (t >> 6);
            T[cl][t & 63] = X2[((size_t)b * 256 + cc * 64 + cl) * NPTS + n0 + (t & 63)];
        }
        __syncthreads();
#pragma unroll
        for (int r = 0; r < 16; ++r) {
            int n_l = wave * 16 + r;
            Xt[((size_t)b * NPTS + n0 + n_l) * 256 + cc * 64 + lane] = T[lane][n_l];
        }
        __syncthreads();
    }
}

// ---------------- fused gather + max over K + partial pool -------------------
__global__ __launch_bounds__(256) void gather_pool_kernel(
    const float* __restrict__ Xt, const int* __restrict__ IDX,
    float* __restrict__ Pp) {
    int b = blockIdx.x, blk = blockIdx.y;
    int wv = threadIdx.x >> 6, lane = threadIdx.x & 63;
    const float* xb = Xt + (size_t)b * NPTS * 256;
    f32x4 sum = (f32x4){0.f, 0.f, 0.f, 0.f};
#pragma unroll 1
    for (int i = 0; i < 4; ++i) {
        int n = blk * 16 + wv * 4 + i;
        const int* idp = IDX + ((size_t)b * NPTS + n) * KNN;
        f32x4 m = *(const f32x4*)(xb + (size_t)idp[0] * 256 + lane * 4);
#pragma unroll
        for (int k = 1; k < KNN; ++k) {
            f32x4 v = *(const f32x4*)(xb + (size_t)idp[k] * 256 + lane * 4);
            m.x = fmaxf(m.x, v.x); m.y = fmaxf(m.y, v.y);
            m.z = fmaxf(m.z, v.z); m.w = fmaxf(m.w, v.w);
        }
        sum.x += m.x; sum.y += m.y; sum.z += m.z; sum.w += m.w;
    }
    __shared__ float S[4][256];
    *(f32x4*)&S[wv][lane * 4] = sum;
    __syncthreads();
    int t = threadIdx.x;
    Pp[((size_t)b * 256 + blk) * 256 + t] = S[0][t] + S[1][t] + S[2][t] + S[3][t];
}

// ---------------- final pool: mean over 256 partials (double) ----------------
__global__ __launch_bounds__(256) void pool_final_kernel(
    const float* __restrict__ Pp, float* __restrict__ P) {
    int b = blockIdx.x, c = threadIdx.x;
    double s = 0.0;
#pragma unroll 4
    for (int j = 0; j < 256; ++j) s += (double)Pp[((size_t)b * 256 + j) * 256 + c];
    P[b * 256 + c] = (float)(s / (double)NPTS);
}

// ---------------- tiny MLP: 256 -> 128 relu -> 64 relu -> 1
__global__ __launch_bounds__(256) void mlp_kernel(
    const float* __restrict__ P,
    const float* __restrict__ gw0, const float* __restrict__ gb0,
    const float* __restrict__ gw1, const float* __restrict__ gb1,
    const float* __restrict__ gw2, const float* __restrict__ gb2,
    float* __restrict__ out) {
    __shared__ float h1[BATCH][128];
    __shared__ float h2[BATCH][64];
    int t = threadIdx.x;
    for (int o = t; o < BATCH * 128; o += 256) {
        int b = o >> 7, j = o & 127;
        const float* p = P + b * 256;
        const float* w = gw0 + j * 256;
        double acc = 0.0;
        for (int c = 0; c < 256; ++c) acc += (double)p[c] * (double)w[c];
        float v = gb0[j] + (float)acc;
        h1[b][j] = v > 0.f ? v : 0.f;
    }
    __syncthreads();
    for (int o = t; o < BATCH * 64; o += 256) {
        int b = o >> 6, j = o & 63;
        const float* w = gw1 + j * 128;
        double acc = 0.0;
        for (int c = 0; c < 128; ++c) acc += (double)h1[b][c] * (double)w[c];
        float v = gb1[j] + (float)acc;
        h2[b][j] = v > 0.f ? v : 0.f;
    }
    __syncthreads();
    if (t < BATCH) {
        double acc = 0.0;
        for (int c = 0; c < 64; ++c) acc += (double)h2[t][c] * (double)gw2[c];
        out[t] = gb2[0] + (float)acc;
    }
}

extern "C" void kernel_launch(void* const* d_in, const int* in_sizes, int n_in,
                              void* d_out, int out_size, void* d_ws, size_t ws_size,
                              hipStream_t stream) {
    const float* pc  = (const float*)d_in[0];
    const float* w0  = (const float*)d_in[1];
    const float* b0  = (const float*)d_in[2];
    const float* g0  = (const float*)d_in[3];
    const float* be0 = (const float*)d_in[4];
    const float* w1  = (const float*)d_in[5];
    const float* b1  = (const float*)d_in[6];
    const float* g1  = (const float*)d_in[7];
    const float* be1 = (const float*)d_in[8];
    const float* w2  = (const float*)d_in[9];
    const float* b2  = (const float*)d_in[10];
    const float* g2  = (const float*)d_in[11];
    const float* be2 = (const float*)d_in[12];
    const float* gw0 = (const float*)d_in[13];
    const float* gb0 = (const float*)d_in[14];
    const float* gw1 = (const float*)d_in[15];
    const float* gb1 = (const float*)d_in[16];
    const float* gw2 = (const float*)d_in[17];
    const float* gb2 = (const float*)d_in[18];
    float* out = (float*)d_out;

    // ws layout (floats). Region reuse timeline:
    //   X0 (2,097,152 f): conv0 act -> DpA -> Pp
    //   X2 (8,388,608 f): conv2 act (live through transpose)
    //   R  (11,534,336 f): X1 (conv1) -> Fc2 (8,388,608 f) + DpB (tail @ +9,437,184)
    //                      -> Xt (8,388,608 f, after knn; doesn't touch DpB)
    float* ws = (float*)d_ws;
    float* X0 = ws;
    float* X2 = X0 + 2097152;
    float* R  = X2 + 8388608;
    float* X1 = R;
    unsigned short* Fc2 = (unsigned short*)R;         // 16,777,216 shorts = 33.5 MB
    float* Xt = R;
    u64* DpA = (u64*)X0;                              // 1,048,576 u64
    u64* DpB = (u64*)(R + 9437184);                   // 1,048,576 u64
    float* Pp = X0;                                   // 524,288 f (after merge4)
    float* SQ = R + 11534336;                         // 32,768 f
    float* P  = SQ + 32768;                           // 2,048 f
    int*  IDX = (int*)(P + 2048);                     // 524,288 i

    conv_kernel<3, 16><<<dim3(NPTS / 256, 64 / 16, BATCH), 256, 0, stream>>>(pc, w0, b0, X0, 64);
    ln_relu_kernel<<<dim3(64, BATCH), 256, 0, stream>>>(X0, g0, be0, 64);
    conv_kernel<64, 32><<<dim3(NPTS / 256, 128 / 32, BATCH), 256, 0, stream>>>(X0, w1, b1, X1, 128);
    ln_relu_kernel<<<dim3(128, BATCH), 256, 0, stream>>>(X1, g1, be1, 128);
    conv_kernel<128, 64><<<dim3(NPTS / 256, 256 / 64, BATCH), 256, 0, stream>>>(X1, w2, b2, X2, 256);
    ln_relu_kernel<<<dim3(256, BATCH), 256, 0, stream>>>(X2, g2, be2, 256);

    convert_kernel<<<dim3(NPTS / 64, BATCH), 256, 0, stream>>>(X2, Fc2, SQ); // overwrites X1 (dead)
    knn_mfma_kernel<<<dim3(BATCH, 32, 4), 256, 0, stream>>>(Fc2, SQ, DpA, DpB);
    knn_merge4_kernel<<<dim3(BATCH * NPTS / 256), 256, 0, stream>>>(DpA, DpB, IDX);
    transpose_kernel<<<dim3(BATCH, NPTS / 64), 256, 0, stream>>>(X2, Xt);   // overwrites Fc2 (dead)
    gather_pool_kernel<<<dim3(BATCH, 256), 256, 0, stream>>>(Xt, IDX, Pp);  // Pp overlays DpA (dead)
    pool_final_kernel<<<dim3(BATCH), 256, 0, stream>>>(Pp, P);
    mlp_kernel<<<1, 256, 0, stream>>>(P, gw0, gb0, gw1, gb1, gw2, gb2, out);
}

// Round 9
// 1335.197 us; speedup vs baseline: 1.2456x; 1.2456x over previous
//
#include <hip/hip_runtime.h>
#include <stdint.h>

#define NPTS 4096
#define BATCH 8
#define KNN 16

typedef __attribute__((ext_vector_type(8))) short short8;
typedef __attribute__((ext_vector_type(4))) float f32x4;
typedef unsigned long long u64;

// ---------------- 1x1 conv: Y[b,co,n] = bias[co] + sum_ci W[co,ci]*X[b,ci,n]
template<int CIN, int COTILE>
__global__ __launch_bounds__(256) void conv_kernel(
    const float* __restrict__ X, const float* __restrict__ W,
    const float* __restrict__ bias, float* __restrict__ Y, int cout) {
    int n = blockIdx.x * 256 + threadIdx.x;
    int co0 = blockIdx.y * COTILE;
    int b = blockIdx.z;
    const float* xb = X + (size_t)b * CIN * NPTS + n;
    float acc[COTILE];
#pragma unroll
    for (int j = 0; j < COTILE; ++j) acc[j] = bias[co0 + j];
    for (int ci = 0; ci < CIN; ++ci) {
        float xv = xb[(size_t)ci * NPTS];
#pragma unroll
        for (int j = 0; j < COTILE; ++j)
            acc[j] = fmaf(W[(co0 + j) * CIN + ci], xv, acc[j]);
    }
#pragma unroll
    for (int j = 0; j < COTILE; ++j)
        Y[((size_t)b * cout + co0 + j) * NPTS + n] = acc[j];
}

// ---------------- LayerNorm over point axis + affine + ReLU, in place -------
__global__ __launch_bounds__(256) void ln_relu_kernel(
    float* __restrict__ X, const float* __restrict__ g,
    const float* __restrict__ be, int C) {
    __shared__ float row_s[NPTS];
    __shared__ double sh[256], sh2[256];
    int c = blockIdx.x, b = blockIdx.y, t = threadIdx.x;
    float* row = X + ((size_t)b * C + c) * NPTS;
    double s = 0.0, s2 = 0.0;
    for (int i = t * 4; i < NPTS; i += 1024) {
        f32x4 v = *(const f32x4*)(row + i);
        *(f32x4*)(row_s + i) = v;
        s += (double)v.x + (double)v.y + (double)v.z + (double)v.w;
        s2 += (double)v.x * v.x + (double)v.y * v.y
            + (double)v.z * v.z + (double)v.w * v.w;
    }
    sh[t] = s; sh2[t] = s2;
    __syncthreads();
    for (int off = 128; off > 0; off >>= 1) {
        if (t < off) { sh[t] += sh[t + off]; sh2[t] += sh2[t + off]; }
        __syncthreads();
    }
    double mu = sh[0] / (double)NPTS;
    double var = sh2[0] / (double)NPTS - mu * mu;
    float rstd = (float)(1.0 / sqrt(var + 1e-5));
    float muf = (float)mu;
    for (int i = t * 4; i < NPTS; i += 1024) {
        f32x4 v = *(const f32x4*)(row_s + i);
        f32x4 gg = *(const f32x4*)(g + i);
        f32x4 bb = *(const f32x4*)(be + i);
        f32x4 o;
        o.x = fmaxf((v.x - muf) * rstd * gg.x + bb.x, 0.f);
        o.y = fmaxf((v.y - muf) * rstd * gg.y + bb.y, 0.f);
        o.z = fmaxf((v.z - muf) * rstd * gg.z + bb.z, 0.f);
        o.w = fmaxf((v.w - muf) * rstd * gg.w + bb.w, 0.f);
        *(f32x4*)(row + i) = o;
    }
}

// ---------------- bf16 hi/lo split conversion + fused squared norms ----------
// X2: [B][256][NPTS] fp32 -> Fc: [B][8][NPTS][72] bf16, SQ[b][n] = sum_c x^2.
// chunk cc (0..3): hi of c = cc*64..+63; chunk 4+cc: lo. Row = 64 payload + 8 pad.
#define ROW_E 72
#define ROW_B 144

__device__ inline unsigned short f2bf_rne(float x) {
    union { float f; unsigned u; } v; v.f = x;
    unsigned u = v.u;
    return (unsigned short)((u + 0x7FFFu + ((u >> 16) & 1u)) >> 16);
}
__device__ inline float bf2f(unsigned short h) {
    union { float f; unsigned u; } v; v.u = ((unsigned)h) << 16;
    return v.f;
}

__global__ __launch_bounds__(256) void convert_kernel(
    const float* __restrict__ X2, unsigned short* __restrict__ Fc,
    float* __restrict__ SQ) {
    __shared__ float T[64][65];
    __shared__ float Q[64][4];
    int b = blockIdx.y;
    int n0 = blockIdx.x * 64;
    int t = threadIdx.x;
    int n_loc = t >> 2, cq = t & 3;
    float sacc = 0.f;
    for (int cc = 0; cc < 4; ++cc) {
        for (int r = 0; r < 16; ++r) {
            int cl = r * 4 + (t >> 6);
            T[cl][t & 63] = X2[((size_t)b * 256 + cc * 64 + cl) * NPTS + n0 + (t & 63)];
        }
        __syncthreads();
        size_t base_hi = (((size_t)(b * 8 + cc) * NPTS) + n0 + n_loc) * ROW_E;
        size_t base_lo = (((size_t)(b * 8 + 4 + cc) * NPTS) + n0 + n_loc) * ROW_E;
#pragma unroll
        for (int j = 0; j < 16; ++j) {
            int c = cq * 16 + j;
            float x = T[c][n_loc];
            sacc = fmaf(x, x, sacc);
            unsigned short h = f2bf_rne(x);
            float lo = x - bf2f(h);
            Fc[base_hi + c] = h;
            Fc[base_lo + c] = f2bf_rne(lo);
        }
        __syncthreads();
    }
    Q[n_loc][cq] = sacc;
    __syncthreads();
    if (t < 64)
        SQ[(size_t)b * NPTS + n0 + t] = Q[t][0] + Q[t][1] + Q[t][2] + Q[t][3];
}

// ---------------- fused MFMA kNN (4-way key split, per-wave selection) -------
// grid (8 batch, 32 q-tiles, 4 key-splits). 4 waves in 2x2 (64q x 64k each).
// K-loop: LDS staging (round-5 proven). Selection: each wave transposes ITS
// acc tile through a PRIVATE 4.4 KB LDS scratch (same-wave lgkmcnt ordering,
// no __syncthreads) and runs filter+ffs-insert for its 64 queries (lane=query).
// Top-16 lists stay in VGPRs (LDS lists = round-8 spill disaster).
#define A_BYTES (128 * ROW_B)        // 18432
#define STAGE_BYTES (2 * A_BYTES)    // 36864
#define SCR_W 69                     // 16 keys x 69 dwords: conflict-free both ways
#define SCR_B (16 * SCR_W * 4)       // 4416
#define SMEM_B (STAGE_BYTES + 4 * SCR_B)  // 54528
#define SENT 0x7F800000FFFFFFFFull   // d=+inf sentinel

__device__ inline void async_cp16(const void* g, void* l) {
    __builtin_amdgcn_global_load_lds((const __attribute__((address_space(1))) void*)g,
                                     (__attribute__((address_space(3))) void*)l, 16, 0, 0);
}

__global__ __launch_bounds__(256) void knn_mfma_kernel(
    const unsigned short* __restrict__ Fc, const float* __restrict__ SQ,
    u64* __restrict__ DpA, u64* __restrict__ DpB) {
    __shared__ __align__(16) char smem[SMEM_B];
    int b = blockIdx.x;
    int q0 = blockIdx.y * 128;
    int ks = blockIdx.z;
    int t = threadIdx.x;
    int lane = t & 63;
    int wv = t >> 6;
    int wq = wv & 1, wk = wv >> 1;
    int quad = lane >> 4;
    int l15 = lane & 15;
    const float* sqb = SQ + (size_t)b * NPTS;
    const char* FcB = (const char*)Fc + (size_t)b * 8 * NPTS * ROW_B;
    float sqn = sqb[q0 + wq * 64 + lane];   // this lane's query self-norm
    float* scr = (float*)(smem + STAGE_BYTES + wv * SCR_B);

    u64 lst[KNN];
#pragma unroll
    for (int j = 0; j < KNN; ++j) lst[j] = SENT;

    for (int kt = 0; kt < 8; ++kt) {
        int kbase = ks * 1024 + kt * 128;
        f32x4 acc[4][4];
#pragma unroll
        for (int i = 0; i < 4; ++i)
#pragma unroll
            for (int j = 0; j < 4; ++j) acc[i][j] = (f32x4){0.f, 0.f, 0.f, 0.f};

        for (int kc = 0; kc < 8; ++kc) {
            __syncthreads();   // previous readers of stage done
            const char* gA = FcB + ((size_t)kc * NPTS + q0) * ROW_B;
            const char* gB = FcB + ((size_t)kc * NPTS + kbase) * ROW_B;
#pragma unroll
            for (int i = 0; i < 9; ++i) {
                int chunk = (i * 4 + wv) * 1024;
                const char* g = (chunk < A_BYTES) ? (gA + chunk) : (gB + (chunk - A_BYTES));
                async_cp16(g + lane * 16, smem + chunk);
            }
            __syncthreads();   // staging drained
#pragma unroll
            for (int kss = 0; kss < 2; ++kss) {
                int coff = kss * 64 + quad * 16;
                short8 a[4], bf[4];
#pragma unroll
                for (int tq = 0; tq < 4; ++tq)
                    a[tq] = *(const short8*)(smem + (wq * 64 + tq * 16 + l15) * ROW_B + coff);
#pragma unroll
                for (int tk = 0; tk < 4; ++tk)
                    bf[tk] = *(const short8*)(smem + A_BYTES + (wk * 64 + tk * 16 + l15) * ROW_B + coff);
#pragma unroll
                for (int tq = 0; tq < 4; ++tq)
#pragma unroll
                    for (int tk = 0; tk < 4; ++tk)
                        acc[tq][tk] = __builtin_amdgcn_mfma_f32_16x16x32_bf16(
                            a[tq], bf[tk], acc[tq][tk], 0, 0, 0);
            }
        }

        // ---- per-wave selection: NO cross-wave barriers ----
        int kwbase = kbase + wk * 64;   // this wave's key range base
#pragma unroll 1
        for (int tk = 0; tk < 4; ++tk) {
            // transpose 16-key slab into private scratch [key][query]
#pragma unroll
            for (int tq = 0; tq < 4; ++tq)
                *(f32x4*)(scr + l15 * SCR_W + tq * 16 + quad * 4) = acc[tq][tk];
            // (compiler inserts lgkmcnt wait; same-wave ordering, no barrier)
            float thrf = __uint_as_float((unsigned)(lst[KNN - 1] >> 32));
            unsigned mask = 0;
#pragma unroll
            for (int j = 0; j < 16; ++j) {
                float gv = scr[j * SCR_W + lane];
                float d = fmaxf(fmaf(-2.f, gv, sqn + sqb[kwbase + tk * 16 + j]), 0.f);
                mask |= (d <= thrf) ? (1u << j) : 0u;
            }
            while (__any((int)(mask != 0u))) {
                if (mask) {
                    int j = __ffs(mask) - 1;
                    mask &= mask - 1u;
                    float gv = scr[j * SCR_W + lane];
                    float d = fmaxf(fmaf(-2.f, gv, sqn + sqb[kwbase + tk * 16 + j]), 0.f);
                    u64 pk = ((u64)__float_as_uint(d) << 32)
                           | (unsigned)(kwbase + tk * 16 + j);
                    if (pk < lst[KNN - 1]) {
                        lst[KNN - 1] = pk;
#pragma unroll
                        for (int s2 = KNN - 1; s2 > 0; --s2) {
                            if (lst[s2] < lst[s2 - 1]) {
                                u64 tmp = lst[s2]; lst[s2] = lst[s2 - 1]; lst[s2 - 1] = tmp;
                            }
                        }
                    }
                }
            }
        }
    }

    // merge the two per-query sublists. t<128: query q0+t, key-half wk=0;
    // t>=128: same queries, wk=1. mls aliases the (dead) stage buffer.
    __syncthreads();
    u64* mls = (u64*)smem;   // [256][17] u64 = 34816 B <= 36864
#pragma unroll
    for (int j = 0; j < KNN; ++j) mls[t * 17 + j] = lst[j];
    __syncthreads();
    if (t < 128) {
        const u64* da = mls + t * 17;
        const u64* db = mls + (t + 128) * 17;
        u64* outp = ((ks < 2) ? DpA : DpB)
                  + ((size_t)((b * NPTS + q0 + t) * 2 + (ks & 1))) * KNN;
        int ia = 0, ib2 = 0;
        for (int k = 0; k < KNN; ++k) {
            bool ta = (ib2 >= KNN) || (ia < KNN && da[ia] < db[ib2]);
            outp[k] = ta ? da[ia++] : db[ib2++];
        }
    }
}

// ---------------- merge 4 key-split partial lists per query ------------------
__global__ __launch_bounds__(256) void knn_merge4_kernel(
    const u64* __restrict__ DpA, const u64* __restrict__ DpB,
    int* __restrict__ IDX) {
    int qg = blockIdx.x * 256 + threadIdx.x;          // [0, B*NPTS)
    const u64* L0 = DpA + (size_t)qg * 2 * KNN;
    const u64* L1 = L0 + KNN;
    const u64* L2 = DpB + (size_t)qg * 2 * KNN;
    const u64* L3 = L2 + KNN;
    int p0 = 0, p1 = 0, p2 = 0, p3 = 0;
    int* outp = IDX + (size_t)qg * KNN;
#pragma unroll 1
    for (int k = 0; k < KNN; ++k) {
        u64 v0 = (p0 < KNN) ? L0[p0] : ~0ull;
        u64 v1 = (p1 < KNN) ? L1[p1] : ~0ull;
        u64 v2 = (p2 < KNN) ? L2[p2] : ~0ull;
        u64 v3 = (p3 < KNN) ? L3[p3] : ~0ull;
        u64 best = v0; int bl = 0;
        if (v1 < best) { best = v1; bl = 1; }
        if (v2 < best) { best = v2; bl = 2; }
        if (v3 < best) { best = v3; bl = 3; }
        outp[k] = (int)(best & 0xffffffffull);
        if (bl == 0) ++p0; else if (bl == 1) ++p1; else if (bl == 2) ++p2; else ++p3;
    }
}

// ---------------- transpose: X2 [b][c][n] -> Xt [b][n][256] ------------------
__global__ __launch_bounds__(256) void transpose_kernel(
    const float* __restrict__ X2, float* __restrict__ Xt) {
    __shared__ float T[64][65];
    int b = blockIdx.x;
    int n0 = blockIdx.y * 64;
    int t = threadIdx.x;
    int wave = t >> 6, lane = t & 63;
    for (int cc = 0; cc < 4; ++cc) {
        for (int r = 0; r < 16; ++r) {
            int cl = r * 4 + (t >> 6);
            T[cl][t & 63] = X2[((size_t)b * 256 + cc * 64 + cl) * NPTS + n0 + (t & 63)];
        }
        __syncthreads();
#pragma unroll
        for (int r = 0; r < 16; ++r) {
            int n_l = wave * 16 + r;
            Xt[((size_t)b * NPTS + n0 + n_l) * 256 + cc * 64 + lane] = T[lane][n_l];
        }
        __syncthreads();
    }
}

// ---------------- fused gather + max over K + partial pool -------------------
__global__ __launch_bounds__(256) void gather_pool_kernel(
    const float* __restrict__ Xt, const int* __restrict__ IDX,
    float* __restrict__ Pp) {
    int b = blockIdx.x, blk = blockIdx.y;
    int wv = threadIdx.x >> 6, lane = threadIdx.x & 63;
    const float* xb = Xt + (size_t)b * NPTS * 256;
    f32x4 sum = (f32x4){0.f, 0.f, 0.f, 0.f};
#pragma unroll 1
    for (int i = 0; i < 4; ++i) {
        int n = blk * 16 + wv * 4 + i;
        const int* idp = IDX + ((size_t)b * NPTS + n) * KNN;
        f32x4 m = *(const f32x4*)(xb + (size_t)idp[0] * 256 + lane * 4);
#pragma unroll
        for (int k = 1; k < KNN; ++k) {
            f32x4 v = *(const f32x4*)(xb + (size_t)idp[k] * 256 + lane * 4);
            m.x = fmaxf(m.x, v.x); m.y = fmaxf(m.y, v.y);
            m.z = fmaxf(m.z, v.z); m.w = fmaxf(m.w, v.w);
        }
        sum.x += m.x; sum.y += m.y; sum.z += m.z; sum.w += m.w;
    }
    __shared__ float S[4][256];
    *(f32x4*)&S[wv][lane * 4] = sum;
    __syncthreads();
    int t = threadIdx.x;
    Pp[((size_t)b * 256 + blk) * 256 + t] = S[0][t] + S[1][t] + S[2][t] + S[3][t];
}

// ---------------- final pool: mean over 256 partials (double) ----------------
__global__ __launch_bounds__(256) void pool_final_kernel(
    const float* __restrict__ Pp, float* __restrict__ P) {
    int b = blockIdx.x, c = threadIdx.x;
    double s = 0.0;
#pragma unroll 4
    for (int j = 0; j < 256; ++j) s += (double)Pp[((size_t)b * 256 + j) * 256 + c];
    P[b * 256 + c] = (float)(s / (double)NPTS);
}

// ---------------- tiny MLP: 256 -> 128 relu -> 64 relu -> 1
__global__ __launch_bounds__(256) void mlp_kernel(
    const float* __restrict__ P,
    const float* __restrict__ gw0, const float* __restrict__ gb0,
    const float* __restrict__ gw1, const float* __restrict__ gb1,
    const float* __restrict__ gw2, const float* __restrict__ gb2,
    float* __restrict__ out) {
    __shared__ float h1[BATCH][128];
    __shared__ float h2[BATCH][64];
    int t = threadIdx.x;
    for (int o = t; o < BATCH * 128; o += 256) {
        int b = o >> 7, j = o & 127;
        const float* p = P + b * 256;
        const float* w = gw0 + j * 256;
        double acc = 0.0;
        for (int c = 0; c < 256; ++c) acc += (double)p[c] * (double)w[c];
        float v = gb0[j] + (float)acc;
        h1[b][j] = v > 0.f ? v : 0.f;
    }
    __syncthreads();
    for (int o = t; o < BATCH * 64; o += 256) {
        int b = o >> 6, j = o & 63;
        const float* w = gw1 + j * 128;
        double acc = 0.0;
        for (int c = 0; c < 128; ++c) acc += (double)h1[b][c] * (double)w[c];
        float v = gb1[j] + (float)acc;
        h2[b][j] = v > 0.f ? v : 0.f;
    }
    __syncthreads();
    if (t < BATCH) {
        double acc = 0.0;
        for (int c = 0; c < 64; ++c) acc += (double)h2[t][c] * (double)gw2[c];
        out[t] = gb2[0] + (float)acc;
    }
}

extern "C" void kernel_launch(void* const* d_in, const int* in_sizes, int n_in,
                              void* d_out, int out_size, void* d_ws, size_t ws_size,
                              hipStream_t stream) {
    const float* pc  = (const float*)d_in[0];
    const float* w0  = (const float*)d_in[1];
    const float* b0  = (const float*)d_in[2];
    const float* g0  = (const float*)d_in[3];
    const float* be0 = (const float*)d_in[4];
    const float* w1  = (const float*)d_in[5];
    const float* b1  = (const float*)d_in[6];
    const float* g1  = (const float*)d_in[7];
    const float* be1 = (const float*)d_in[8];
    const float* w2  = (const float*)d_in[9];
    const float* b2  = (const float*)d_in[10];
    const float* g2  = (const float*)d_in[11];
    const float* be2 = (const float*)d_in[12];
    const float* gw0 = (const float*)d_in[13];
    const float* gb0 = (const float*)d_in[14];
    const float* gw1 = (const float*)d_in[15];
    const float* gb1 = (const float*)d_in[16];
    const float* gw2 = (const float*)d_in[17];
    const float* gb2 = (const float*)d_in[18];
    float* out = (float*)d_out;

    // ws layout (floats). Region reuse timeline:
    //   X0 (2,097,152 f): conv0 act -> DpA -> Pp
    //   X2 (8,388,608 f): conv2 act (live through transpose)
    //   R  (11,534,336 f): X1 (conv1) -> Fc (9,437,184 f) + DpB (tail @ +9,437,184)
    //                      -> Xt (8,388,608 f, after knn; doesn't touch DpB)
    float* ws = (float*)d_ws;
    float* X0 = ws;
    float* X2 = X0 + 2097152;
    float* R  = X2 + 8388608;
    float* X1 = R;
    unsigned short* Fc = (unsigned short*)R;          // 18,874,368 shorts
    float* Xt = R;
    u64* DpA = (u64*)X0;                              // 1,048,576 u64
    u64* DpB = (u64*)(R + 9437184);                   // 1,048,576 u64
    float* Pp = X0;                                   // 524,288 f (after merge4)
    float* SQ = R + 11534336;                         // 32,768 f
    float* P  = SQ + 32768;                           // 2,048 f
    int*  IDX = (int*)(P + 2048);                     // 524,288 i

    conv_kernel<3, 16><<<dim3(NPTS / 256, 64 / 16, BATCH), 256, 0, stream>>>(pc, w0, b0, X0, 64);
    ln_relu_kernel<<<dim3(64, BATCH), 256, 0, stream>>>(X0, g0, be0, 64);
    conv_kernel<64, 32><<<dim3(NPTS / 256, 128 / 32, BATCH), 256, 0, stream>>>(X0, w1, b1, X1, 128);
    ln_relu_kernel<<<dim3(128, BATCH), 256, 0, stream>>>(X1, g1, be1, 128);
    conv_kernel<128, 64><<<dim3(NPTS / 256, 256 / 64, BATCH), 256, 0, stream>>>(X1, w2, b2, X2, 256);
    ln_relu_kernel<<<dim3(256, BATCH), 256, 0, stream>>>(X2, g2, be2, 256);

    convert_kernel<<<dim3(NPTS / 64, BATCH), 256, 0, stream>>>(X2, Fc, SQ); // overwrites X1 (dead)
    knn_mfma_kernel<<<dim3(BATCH, 32, 4), 256, 0, stream>>>(Fc, SQ, DpA, DpB);
    knn_merge4_kernel<<<dim3(BATCH * NPTS / 256), 256, 0, stream>>>(DpA, DpB, IDX);
    transpose_kernel<<<dim3(BATCH, NPTS / 64), 256, 0, stream>>>(X2, Xt);   // overwrites Fc (dead)
    gather_pool_kernel<<<dim3(BATCH, 256), 256, 0, stream>>>(Xt, IDX, Pp);  // Pp overlays DpA (dead)
    pool_final_kernel<<<dim3(BATCH), 256, 0, stream>>>(Pp, P);
    mlp_kernel<<<1, 256, 0, stream>>>(P, gw0, gb0, gw1, gb1, gw2, gb2, out);
}

// Round 10
// 753.093 us; speedup vs baseline: 2.2084x; 1.7730x over previous
//
#include <hip/hip_runtime.h>
#include <stdint.h>

#define NPTS 4096
#define BATCH 8
#define KNN 16

typedef __attribute__((ext_vector_type(8))) short short8;
typedef __attribute__((ext_vector_type(4))) float f32x4;
typedef unsigned long long u64;

// ---------------- 1x1 conv: Y[b,co,n] = bias[co] + sum_ci W[co,ci]*X[b,ci,n]
template<int CIN, int COTILE>
__global__ __launch_bounds__(256) void conv_kernel(
    const float* __restrict__ X, const float* __restrict__ W,
    const float* __restrict__ bias, float* __restrict__ Y, int cout) {
    int n = blockIdx.x * 256 + threadIdx.x;
    int co0 = blockIdx.y * COTILE;
    int b = blockIdx.z;
    const float* xb = X + (size_t)b * CIN * NPTS + n;
    float acc[COTILE];
#pragma unroll
    for (int j = 0; j < COTILE; ++j) acc[j] = bias[co0 + j];
    for (int ci = 0; ci < CIN; ++ci) {
        float xv = xb[(size_t)ci * NPTS];
#pragma unroll
        for (int j = 0; j < COTILE; ++j)
            acc[j] = fmaf(W[(co0 + j) * CIN + ci], xv, acc[j]);
    }
#pragma unroll
    for (int j = 0; j < COTILE; ++j)
        Y[((size_t)b * cout + co0 + j) * NPTS + n] = acc[j];
}

// ---------------- LayerNorm over point axis + affine + ReLU, in place -------
// Row (16 KB) cached in LDS: one global read pass instead of two.
__global__ __launch_bounds__(256) void ln_relu_kernel(
    float* __restrict__ X, const float* __restrict__ g,
    const float* __restrict__ be, int C) {
    __shared__ float row_s[NPTS];
    __shared__ double sh[256], sh2[256];
    int c = blockIdx.x, b = blockIdx.y, t = threadIdx.x;
    float* row = X + ((size_t)b * C + c) * NPTS;
    double s = 0.0, s2 = 0.0;
    for (int i = t * 4; i < NPTS; i += 1024) {
        f32x4 v = *(const f32x4*)(row + i);
        *(f32x4*)(row_s + i) = v;
        s += (double)v.x + (double)v.y + (double)v.z + (double)v.w;
        s2 += (double)v.x * v.x + (double)v.y * v.y
            + (double)v.z * v.z + (double)v.w * v.w;
    }
    sh[t] = s; sh2[t] = s2;
    __syncthreads();
    for (int off = 128; off > 0; off >>= 1) {
        if (t < off) { sh[t] += sh[t + off]; sh2[t] += sh2[t + off]; }
        __syncthreads();
    }
    double mu = sh[0] / (double)NPTS;
    double var = sh2[0] / (double)NPTS - mu * mu;
    float rstd = (float)(1.0 / sqrt(var + 1e-5));
    float muf = (float)mu;
    for (int i = t * 4; i < NPTS; i += 1024) {
        f32x4 v = *(const f32x4*)(row_s + i);
        f32x4 gg = *(const f32x4*)(g + i);
        f32x4 bb = *(const f32x4*)(be + i);
        f32x4 o;
        o.x = fmaxf((v.x - muf) * rstd * gg.x + bb.x, 0.f);
        o.y = fmaxf((v.y - muf) * rstd * gg.y + bb.y, 0.f);
        o.z = fmaxf((v.z - muf) * rstd * gg.z + bb.z, 0.f);
        o.w = fmaxf((v.w - muf) * rstd * gg.w + bb.w, 0.f);
        *(f32x4*)(row + i) = o;
    }
}

// ---------------- bf16 hi/lo split conversion + fused squared norms ----------
// X2: [B][256][NPTS] fp32 -> Fc: [B][8][NPTS][72] bf16, SQ[b][n] = sum_c x^2.
// chunk cc (0..3): hi of c = cc*64..+63; chunk 4+cc: lo. Row = 64 payload + 8 pad.
#define ROW_E 72
#define ROW_B 144

__device__ inline unsigned short f2bf_rne(float x) {
    union { float f; unsigned u; } v; v.f = x;
    unsigned u = v.u;
    return (unsigned short)((u + 0x7FFFu + ((u >> 16) & 1u)) >> 16);
}
__device__ inline float bf2f(unsigned short h) {
    union { float f; unsigned u; } v; v.u = ((unsigned)h) << 16;
    return v.f;
}

__global__ __launch_bounds__(256) void convert_kernel(
    const float* __restrict__ X2, unsigned short* __restrict__ Fc,
    float* __restrict__ SQ) {
    __shared__ float T[64][65];
    __shared__ float Q[64][4];
    int b = blockIdx.y;
    int n0 = blockIdx.x * 64;
    int t = threadIdx.x;
    int n_loc = t >> 2, cq = t & 3;
    float sacc = 0.f;
    for (int cc = 0; cc < 4; ++cc) {
        for (int r = 0; r < 16; ++r) {
            int cl = r * 4 + (t >> 6);
            T[cl][t & 63] = X2[((size_t)b * 256 + cc * 64 + cl) * NPTS + n0 + (t & 63)];
        }
        __syncthreads();
        size_t base_hi = (((size_t)(b * 8 + cc) * NPTS) + n0 + n_loc) * ROW_E;
        size_t base_lo = (((size_t)(b * 8 + 4 + cc) * NPTS) + n0 + n_loc) * ROW_E;
#pragma unroll
        for (int j = 0; j < 16; ++j) {
            int c = cq * 16 + j;
            float x = T[c][n_loc];
            sacc = fmaf(x, x, sacc);
            unsigned short h = f2bf_rne(x);
            float lo = x - bf2f(h);
            Fc[base_hi + c] = h;
            Fc[base_lo + c] = f2bf_rne(lo);
        }
        __syncthreads();
    }
    Q[n_loc][cq] = sacc;
    __syncthreads();
    if (t < 64)
        SQ[(size_t)b * NPTS + n0 + t] = Q[t][0] + Q[t][1] + Q[t][2] + Q[t][3];
}

// ---------------- fused MFMA kNN (4-way key split, packed u64 lists) ---------
// VERBATIM round-5 structure (empirical optimum: 414 us). grid (8 batch,
// 32 q-tiles, 4 key-splits): linear id % 8 == batch -> XCD-local Fc.
// 256 threads = 4 waves, 2x2 of 64q x 64k. d = max(sqn + sq[m] - 2*G, 0);
// packed = (bits(d)<<32)|idx is uint64-monotone == lax.top_k (-d) order.
#define A_BYTES (128 * ROW_B)        // 18432
#define STAGE_BYTES (2 * A_BYTES)    // 36864
#define SENT 0x7F800000FFFFFFFFull   // d=+inf sentinel

__device__ inline void async_cp16(const void* g, void* l) {
    __builtin_amdgcn_global_load_lds((const __attribute__((address_space(1))) void*)g,
                                     (__attribute__((address_space(3))) void*)l, 16, 0, 0);
}

__global__ __launch_bounds__(256) void knn_mfma_kernel(
    const unsigned short* __restrict__ Fc, const float* __restrict__ SQ,
    u64* __restrict__ DpA, u64* __restrict__ DpB) {
    __shared__ __align__(16) char smem[STAGE_BYTES];   // union: stage A|B, Gbuf, merge
    int b = blockIdx.x;
    int q0 = blockIdx.y * 128;
    int ks = blockIdx.z;
    int t = threadIdx.x;
    int lane = t & 63;
    int wv = t >> 6;
    int wq = wv & 1, wk = wv >> 1;
    int quad = lane >> 4;
    int l15 = lane & 15;
    const float* sqb = SQ + (size_t)b * NPTS;
    const char* FcB = (const char*)Fc + (size_t)b * 8 * NPTS * ROW_B;
    float sqn = sqb[q0 + (t & 127)];   // this thread's query self-norm

    u64 lst[KNN];
#pragma unroll
    for (int j = 0; j < KNN; ++j) lst[j] = SENT;

    for (int kt = 0; kt < 8; ++kt) {
        int kbase = ks * 1024 + kt * 128;
        f32x4 acc[4][4];
#pragma unroll
        for (int i = 0; i < 4; ++i)
#pragma unroll
            for (int j = 0; j < 4; ++j) acc[i][j] = (f32x4){0.f, 0.f, 0.f, 0.f};

        for (int kc = 0; kc < 8; ++kc) {
            __syncthreads();   // previous readers of smem done
            const char* gA = FcB + ((size_t)kc * NPTS + q0) * ROW_B;
            const char* gB = FcB + ((size_t)kc * NPTS + kbase) * ROW_B;
#pragma unroll
            for (int i = 0; i < 9; ++i) {
                int chunk = (i * 4 + wv) * 1024;
                const char* g = (chunk < A_BYTES) ? (gA + chunk) : (gB + (chunk - A_BYTES));
                async_cp16(g + lane * 16, smem + chunk);
            }
            __syncthreads();   // staging drained
#pragma unroll
            for (int kss = 0; kss < 2; ++kss) {
                int coff = kss * 64 + quad * 16;
                short8 a[4], bf[4];
#pragma unroll
                for (int tq = 0; tq < 4; ++tq)
                    a[tq] = *(const short8*)(smem + (wq * 64 + tq * 16 + l15) * ROW_B + coff);
#pragma unroll
                for (int tk = 0; tk < 4; ++tk)
                    bf[tk] = *(const short8*)(smem + A_BYTES + (wk * 64 + tk * 16 + l15) * ROW_B + coff);
#pragma unroll
                for (int tq = 0; tq < 4; ++tq)
#pragma unroll
                    for (int tk = 0; tk < 4; ++tk)
                        acc[tq][tk] = __builtin_amdgcn_mfma_f32_16x16x32_bf16(
                            a[tq], bf[tk], acc[tq][tk], 0, 0, 0);
            }
        }

        // selection: two 64-key halves through LDS [key][query+pad] stride 132
        float* Gbuf = (float*)smem;
        int q = t & 127, sub = t >> 7;
#pragma unroll 1
        for (int h = 0; h < 2; ++h) {
            __syncthreads();   // previous phase's Gbuf reads done
            if (wk == h) {
#pragma unroll
                for (int tk = 0; tk < 4; ++tk) {
                    int klocal = tk * 16 + l15;
#pragma unroll
                    for (int tq = 0; tq < 4; ++tq)
                        *(f32x4*)(Gbuf + klocal * 132 + wq * 64 + tq * 16 + quad * 4) = acc[tq][tk];
                }
            }
            __syncthreads();
            // phase 1: uniform-cost filter, store true distance back in place
            float* gq = Gbuf + sub * 32 * 132 + q;
            float thrf = __uint_as_float((unsigned)(lst[KNN - 1] >> 32));
            unsigned mask = 0;
#pragma unroll
            for (int j = 0; j < 32; ++j) {
                float gv = gq[j * 132];
                float d = fmaxf(fmaf(-2.f, gv, sqn + sqb[kbase + h * 64 + sub * 32 + j]), 0.f);
                gq[j * 132] = d;
                mask |= (d <= thrf) ? (1u << j) : 0u;
            }
            // phase 2: process only candidates (wave cost = max popcount over lanes)
            while (__any((int)(mask != 0u))) {
                if (mask) {
                    int j = __ffs(mask) - 1;
                    mask &= mask - 1u;
                    float d = gq[j * 132];
                    u64 pk = ((u64)__float_as_uint(d) << 32)
                           | (unsigned)(kbase + h * 64 + sub * 32 + j);
                    if (pk < lst[KNN - 1]) {
                        lst[KNN - 1] = pk;
#pragma unroll
                        for (int s = KNN - 1; s > 0; --s) {
                            if (lst[s] < lst[s - 1]) {
                                u64 tmp = lst[s]; lst[s] = lst[s - 1]; lst[s - 1] = tmp;
                            }
                        }
                    }
                }
            }
        }
    }

    // merge the two per-query sublists (threads t and t+128)
    __syncthreads();
    u64* mls = (u64*)smem;   // [256][17] u64 = 34816 B
#pragma unroll
    for (int j = 0; j < KNN; ++j) mls[t * 17 + j] = lst[j];
    __syncthreads();
    if (t < 128) {
        const u64* da = mls + t * 17;
        const u64* db = mls + (t + 128) * 17;
        u64* outp = ((ks < 2) ? DpA : DpB)
                  + ((size_t)((b * NPTS + q0 + t) * 2 + (ks & 1))) * KNN;
        int ia = 0, ib2 = 0;
        for (int k = 0; k < KNN; ++k) {
            bool ta = (ib2 >= KNN) || (ia < KNN && da[ia] < db[ib2]);
            outp[k] = ta ? da[ia++] : db[ib2++];
        }
    }
}

// ---------------- transpose: X2 [b][c][n] -> Xt [b][n][256] ------------------
__global__ __launch_bounds__(256) void transpose_kernel(
    const float* __restrict__ X2, float* __restrict__ Xt) {
    __shared__ float T[64][65];
    int b = blockIdx.x;
    int n0 = blockIdx.y * 64;
    int t = threadIdx.x;
    int wave = t >> 6, lane = t & 63;
    for (int cc = 0; cc < 4; ++cc) {
        for (int r = 0; r < 16; ++r) {
            int cl = r * 4 + (t >> 6);
            T[cl][t & 63] = X2[((size_t)b * 256 + cc * 64 + cl) * NPTS + n0 + (t & 63)];
        }
        __syncthreads();
#pragma unroll
        for (int r = 0; r < 16; ++r) {
            int n_l = wave * 16 + r;
            Xt[((size_t)b * NPTS + n0 + n_l) * 256 + cc * 64 + lane] = T[lane][n_l];
        }
        __syncthreads();
    }
}

// ---------------- fused merge4 + gather + max over K + partial pool ----------
// grid (8, 256): block handles 16 points. Phase 1: threads 0-15 merge the 4
// key-split partial lists for their point (lexicographic u64 = lax.top_k order)
// into LDS. Phase 2: wave = 4 points, lanes = 64 c-quads, gather+max+sum.
__global__ __launch_bounds__(256) void gather_pool_kernel(
    const float* __restrict__ Xt, const u64* __restrict__ DpA,
    const u64* __restrict__ DpB, float* __restrict__ Pp) {
    __shared__ int idxs[16][KNN];
    int b = blockIdx.x, blk = blockIdx.y;
    int t = threadIdx.x;
    if (t < 16) {
        int qg = b * NPTS + blk * 16 + t;
        const u64* L0 = DpA + (size_t)qg * 2 * KNN;
        const u64* L1 = L0 + KNN;
        const u64* L2 = DpB + (size_t)qg * 2 * KNN;
        const u64* L3 = L2 + KNN;
        int p0 = 0, p1 = 0, p2 = 0, p3 = 0;
#pragma unroll 1
        for (int k = 0; k < KNN; ++k) {
            u64 v0 = (p0 < KNN) ? L0[p0] : ~0ull;
            u64 v1 = (p1 < KNN) ? L1[p1] : ~0ull;
            u64 v2 = (p2 < KNN) ? L2[p2] : ~0ull;
            u64 v3 = (p3 < KNN) ? L3[p3] : ~0ull;
            u64 best = v0; int bl = 0;
            if (v1 < best) { best = v1; bl = 1; }
            if (v2 < best) { best = v2; bl = 2; }
            if (v3 < best) { best = v3; bl = 3; }
            idxs[t][k] = (int)(best & 0xffffffffull);
            if (bl == 0) ++p0; else if (bl == 1) ++p1; else if (bl == 2) ++p2; else ++p3;
        }
    }
    __syncthreads();
    int wv = t >> 6, lane = t & 63;
    const float* xb = Xt + (size_t)b * NPTS * 256;
    f32x4 sum = (f32x4){0.f, 0.f, 0.f, 0.f};
#pragma unroll 1
    for (int i = 0; i < 4; ++i) {
        const int* idp = idxs[wv * 4 + i];
        f32x4 m = *(const f32x4*)(xb + (size_t)idp[0] * 256 + lane * 4);
#pragma unroll
        for (int k = 1; k < KNN; ++k) {
            f32x4 v = *(const f32x4*)(xb + (size_t)idp[k] * 256 + lane * 4);
            m.x = fmaxf(m.x, v.x); m.y = fmaxf(m.y, v.y);
            m.z = fmaxf(m.z, v.z); m.w = fmaxf(m.w, v.w);
        }
        sum.x += m.x; sum.y += m.y; sum.z += m.z; sum.w += m.w;
    }
    __shared__ float S[4][256];
    *(f32x4*)&S[wv][lane * 4] = sum;
    __syncthreads();
    Pp[((size_t)b * 256 + blk) * 256 + t] = S[0][t] + S[1][t] + S[2][t] + S[3][t];
}

// ---------------- final pool: mean over 256 partials (double) ----------------
__global__ __launch_bounds__(256) void pool_final_kernel(
    const float* __restrict__ Pp, float* __restrict__ P) {
    int b = blockIdx.x, c = threadIdx.x;
    double s = 0.0;
#pragma unroll 4
    for (int j = 0; j < 256; ++j) s += (double)Pp[((size_t)b * 256 + j) * 256 + c];
    P[b * 256 + c] = (float)(s / (double)NPTS);
}

// ---------------- tiny MLP: 256 -> 128 relu -> 64 relu -> 1
__global__ __launch_bounds__(256) void mlp_kernel(
    const float* __restrict__ P,
    const float* __restrict__ gw0, const float* __restrict__ gb0,
    const float* __restrict__ gw1, const float* __restrict__ gb1,
    const float* __restrict__ gw2, const float* __restrict__ gb2,
    float* __restrict__ out) {
    __shared__ float h1[BATCH][128];
    __shared__ float h2[BATCH][64];
    int t = threadIdx.x;
    for (int o = t; o < BATCH * 128; o += 256) {
        int b = o >> 7, j = o & 127;
        const float* p = P + b * 256;
        const float* w = gw0 + j * 256;
        double acc = 0.0;
        for (int c = 0; c < 256; ++c) acc += (double)p[c] * (double)w[c];
        float v = gb0[j] + (float)acc;
        h1[b][j] = v > 0.f ? v : 0.f;
    }
    __syncthreads();
    for (int o = t; o < BATCH * 64; o += 256) {
        int b = o >> 6, j = o & 63;
        const float* w = gw1 + j * 128;
        double acc = 0.0;
        for (int c = 0; c < 128; ++c) acc += (double)h1[b][c] * (double)w[c];
        float v = gb1[j] + (float)acc;
        h2[b][j] = v > 0.f ? v : 0.f;
    }
    __syncthreads();
    if (t < BATCH) {
        double acc = 0.0;
        for (int c = 0; c < 64; ++c) acc += (double)h2[t][c] * (double)gw2[c];
        out[t] = gb2[0] + (float)acc;
    }
}

extern "C" void kernel_launch(void* const* d_in, const int* in_sizes, int n_in,
                              void* d_out, int out_size, void* d_ws, size_t ws_size,
                              hipStream_t stream) {
    const float* pc  = (const float*)d_in[0];
    const float* w0  = (const float*)d_in[1];
    const float* b0  = (const float*)d_in[2];
    const float* g0  = (const float*)d_in[3];
    const float* be0 = (const float*)d_in[4];
    const float* w1  = (const float*)d_in[5];
    const float* b1  = (const float*)d_in[6];
    const float* g1  = (const float*)d_in[7];
    const float* be1 = (const float*)d_in[8];
    const float* w2  = (const float*)d_in[9];
    const float* b2  = (const float*)d_in[10];
    const float* g2  = (const float*)d_in[11];
    const float* be2 = (const float*)d_in[12];
    const float* gw0 = (const float*)d_in[13];
    const float* gb0 = (const float*)d_in[14];
    const float* gw1 = (const float*)d_in[15];
    const float* gb1 = (const float*)d_in[16];
    const float* gw2 = (const float*)d_in[17];
    const float* gb2 = (const float*)d_in[18];
    float* out = (float*)d_out;

    // ws layout (floats). Region reuse timeline:
    //   X0 (2,097,152 f): conv0 act -> DpA (knn ks 0-1 packed lists; live
    //                     through gather_pool)
    //   X2 (8,388,608 f): conv2 act (live through transpose)
    //   R  (11,534,336 f): X1 (conv1) -> Fc (9,437,184 f) + DpB (tail @ +9,437,184)
    //                      -> Xt (8,388,608 f, after knn; doesn't touch DpB)
    //   tail: SQ, P, Pp (Pp in old IDX slot; no region conflict with DpA/DpB)
    float* ws = (float*)d_ws;
    float* X0 = ws;
    float* X2 = X0 + 2097152;
    float* R  = X2 + 8388608;
    float* X1 = R;
    unsigned short* Fc = (unsigned short*)R;          // 18,874,368 shorts
    float* Xt = R;
    u64* DpA = (u64*)X0;                              // 1,048,576 u64
    u64* DpB = (u64*)(R + 9437184);                   // 1,048,576 u64
    float* SQ = R + 11534336;                         // 32,768 f
    float* P  = SQ + 32768;                           // 2,048 f
    float* Pp = P + 2048;                             // 524,288 f

    conv_kernel<3, 16><<<dim3(NPTS / 256, 64 / 16, BATCH), 256, 0, stream>>>(pc, w0, b0, X0, 64);
    ln_relu_kernel<<<dim3(64, BATCH), 256, 0, stream>>>(X0, g0, be0, 64);
    conv_kernel<64, 32><<<dim3(NPTS / 256, 128 / 32, BATCH), 256, 0, stream>>>(X0, w1, b1, X1, 128);
    ln_relu_kernel<<<dim3(128, BATCH), 256, 0, stream>>>(X1, g1, be1, 128);
    conv_kernel<128, 64><<<dim3(NPTS / 256, 256 / 64, BATCH), 256, 0, stream>>>(X1, w2, b2, X2, 256);
    ln_relu_kernel<<<dim3(256, BATCH), 256, 0, stream>>>(X2, g2, be2, 256);

    convert_kernel<<<dim3(NPTS / 64, BATCH), 256, 0, stream>>>(X2, Fc, SQ); // overwrites X1 (dead)
    knn_mfma_kernel<<<dim3(BATCH, 32, 4), 256, 0, stream>>>(Fc, SQ, DpA, DpB);
    transpose_kernel<<<dim3(BATCH, NPTS / 64), 256, 0, stream>>>(X2, Xt);   // overwrites Fc (dead)
    gather_pool_kernel<<<dim3(BATCH, 256), 256, 0, stream>>>(Xt, DpA, DpB, Pp);
    pool_final_kernel<<<dim3(BATCH), 256, 0, stream>>>(Pp, P);
    mlp_kernel<<<1, 256, 0, stream>>>(P, gw0, gb0, gw1, gb1, gw2, gb2, out);
}